// Round 8
// baseline (106.917 us; speedup 1.0000x reference)
//
#include <hip/hip_runtime.h>
#include <hip/hip_bf16.h>

#define BATCH 2048
#define IDIM  256
#define ODIM  64
#define GRIDN 300

typedef __bf16 bf16x8 __attribute__((ext_vector_type(8)));
typedef float  f32x16 __attribute__((ext_vector_type(16)));
typedef float  f32x2  __attribute__((ext_vector_type(2)));
typedef unsigned int uint4v __attribute__((ext_vector_type(4)));

#define AS1 __attribute__((address_space(1)))
#define AS3 __attribute__((address_space(3)))

// NO unions in hot paths (R4/R5/R6 lesson: memory-typed aggregates scratch-
// demote -> 0.5-1.6GB scratch traffic). Vectors + bit_cast only.
__device__ __forceinline__ unsigned short f2bf(float f) {
    return __builtin_bit_cast(unsigned short, __float2bfloat16(f));  // RNE
}

// ---------------------------------------------------------------------------
// Prep (unchanged — proven): fouriercoeffs [2][64][256][300] f32 -> WP bf16
// 4KB chunks, one per (isplit ib, g).
// In-chunk byte = q*1024 + j*16 + (il&3)*4 + t*2, q = il>>2.
// ---------------------------------------------------------------------------
__global__ __launch_bounds__(256) void fkan_prep(const float* __restrict__ fc,
                                                 char* __restrict__ wp) {
    __shared__ alignas(16) char lds[32768];
    const int blk = blockIdx.x;
    const int ib  = blk & 15;          // i-split 0..15
    const int gb  = blk >> 4;          // 0..37
    const int g0  = gb * 8;
    const int G   = (gb == 37) ? 4 : 8;   // 300 = 37*8 + 4
    const int q   = threadIdx.x >> 6;     // wave = il quad
    const int j   = threadIdx.x & 63;     // lane = output col

    float vals[2][4][8];
    #pragma unroll
    for (int t = 0; t < 2; ++t) {
        #pragma unroll
        for (int e = 0; e < 4; ++e) {
            const float* src = fc + (((size_t)t * ODIM + j) * IDIM
                                     + (ib * 16 + q * 4 + e)) * GRIDN + g0;
            float4 lo = *(const float4*)(src);
            vals[t][e][0] = lo.x; vals[t][e][1] = lo.y;
            vals[t][e][2] = lo.z; vals[t][e][3] = lo.w;
            if (G == 8) {
                float4 hi = *(const float4*)(src + 4);
                vals[t][e][4] = hi.x; vals[t][e][5] = hi.y;
                vals[t][e][6] = hi.z; vals[t][e][7] = hi.w;
            }
        }
    }
    #pragma unroll
    for (int g = 0; g < 8; ++g) {
        if (g < 4 || G == 8) {
            uint4v dw;
            #pragma unroll
            for (int e = 0; e < 4; ++e)
                dw[e] = (unsigned)f2bf(vals[0][e][g]) | ((unsigned)f2bf(vals[1][e][g]) << 16);
            *(uint4v*)(lds + g * 4096 + q * 1024 + j * 16) = dw;
        }
    }
    __syncthreads();
    char* dst = wp + ((size_t)ib * GRIDN + g0) * 4096;
    for (int w = threadIdx.x * 16; w < G * 4096; w += 256 * 16)
        *(uint4v*)(dst + w) = *(const uint4v*)(lds + w);
}

// ---------------------------------------------------------------------------
// Main — R7's proven union-free structure, retuned for residency + VALU:
//  * 3-g (12KB) stages, LDS 2x12KB = 24KB/block -> 5 blocks/CU co-resident
//    (R7's 40KB blocks: only 3/CU fit -> ragged grid, 29% occupancy).
//  * g split 5 ways (60 each): grid 1280 = exactly 5 blocks/CU, balanced.
//  * launch_bounds(256,5): allocator targets <=102 regs/wave
//    (64 VGPR + 32 AGPR = 96 fits -> 5 waves/SIMD TLP).
//  * recurrence states as f32x2 -> v_pk_fma_f32 (halves recurrence VALU).
// Race-free as R7: next-stage DMAs issued after the barrier that sealed all
// reads of the destination buffer (plain __syncthreads, no asm).
// Grid mapping: xcd = bid&7; each XCD's 160 blocks touch exactly 2 isplits
// (2 x 1.2MB weight slice -> L2-resident).
// ---------------------------------------------------------------------------
__global__ __launch_bounds__(256, 5) void fkan_main(const float* __restrict__ x,
                                                    const char* __restrict__ wp,
                                                    float* __restrict__ out) {
    __shared__ alignas(16) char lds[2][12288];

    const int bid    = blockIdx.x;               // 0..1279
    const int xcd    = bid & 7;
    const int within = bid >> 3;                 // 0..159
    const int slice  = xcd * 10 + within % 10;   // 0..79  (isplit x gq)
    const int mtile  = within / 10;              // 0..15
    const int isplit = slice / 5;                // 0..15
    const int gq     = slice % 5;                // 0..4
    const int g_begin = gq * 60;

    const int tid  = threadIdx.x;
    const int wave = tid >> 6;
    const int lane = tid & 63;
    const int l31  = lane & 31;
    const int kgrp = lane >> 5;
    const int row  = mtile * 128 + wave * 32 + l31;   // batch row (A lane row)

    // --- init 8 recurrence states, packed as f32x2 (v_pk_fma_f32 path) ---
    // state ss = h*4+p  <->  il = h*8 + kgrp*4 + p;  vc[ss>>1][ss&1] = cos
    f32x2 vc[4], vs[4], vbc[4], vbs[4];
    const float* xrow = x + (size_t)row * IDIM + isplit * 16;
    #pragma unroll
    for (int h = 0; h < 2; ++h) {
        const float4 xv4 = *(const float4*)(xrow + h * 8 + kgrp * 4);
        float xa[4] = {xv4.x, xv4.y, xv4.z, xv4.w};
        #pragma unroll
        for (int p = 0; p < 4; ++p) {
            const int ss = h * 4 + p;
            const float xv = xa[p];
            float sb, cb;
            __sincosf(xv, &sb, &cb);
            vbc[ss >> 1][ss & 1] = cb; vbs[ss >> 1][ss & 1] = sb;
            float s0 = sb, c0 = cb;
            if (g_begin != 0) __sincosf((float)(g_begin + 1) * xv, &s0, &c0);
            vc[ss >> 1][ss & 1] = c0; vs[ss >> 1][ss & 1] = s0;
        }
    }

    // B-frag read base inside a 4KB g-slice: q*1024 + j*16, q = kchunk*2+kgrp
    const unsigned aq = (unsigned)kgrp * 1024 + (unsigned)l31 * 16;
    const char* wbase = wp + ((size_t)(isplit * GRIDN + g_begin)) * 4096 + tid * 16;

    // prologue: stage iter-0's 3 g-slices (12KB) into buf 0
    #pragma unroll
    for (int p = 0; p < 3; ++p)
        __builtin_amdgcn_global_load_lds(
            (const AS1 unsigned int*)(wbase + (size_t)p * 4096),
            (AS3 unsigned int*)(&lds[0][0] + p * 4096 + tid * 16), 16, 0, 0);
    __syncthreads();

    f32x16 acc0 = {0,0,0,0,0,0,0,0,0,0,0,0,0,0,0,0};
    f32x16 acc1 = {0,0,0,0,0,0,0,0,0,0,0,0,0,0,0,0};

    for (int it = 0; it < 20; ++it) {
        const int cur = it & 1;
        // issue next 12KB stage; destination buffer's reads were sealed by the
        // previous iteration's __syncthreads (vm+lgkm drained for all waves)
        if (it + 1 < 20) {
            #pragma unroll
            for (int p = 0; p < 3; ++p)
                __builtin_amdgcn_global_load_lds(
                    (const AS1 unsigned int*)(wbase + ((size_t)(it + 1) * 3 + p) * 4096),
                    (AS3 unsigned int*)(&lds[cur ^ 1][0] + p * 4096 + tid * 16),
                    16, 0, 0);
        }
        #pragma unroll
        for (int g = 0; g < 3; ++g) {
            const char* base = &lds[cur][0] + g * 4096;
            const bf16x8 b00 = *(const bf16x8*)(base + aq);           // kc0, cols 0..31
            const bf16x8 b01 = *(const bf16x8*)(base + aq + 512);     // kc0, cols 32..63
            const bf16x8 b10 = *(const bf16x8*)(base + aq + 2048);    // kc1, cols 0..31
            const bf16x8 b11 = *(const bf16x8*)(base + aq + 2560);    // kc1, cols 32..63
            uint4v a1, a2;
            #pragma unroll
            for (int p = 0; p < 4; ++p) {
                a1[p] = (unsigned)f2bf(vc[p >> 1][p & 1])
                      | ((unsigned)f2bf(vs[p >> 1][p & 1]) << 16);
                a2[p] = (unsigned)f2bf(vc[(4 + p) >> 1][p & 1])
                      | ((unsigned)f2bf(vs[(4 + p) >> 1][p & 1]) << 16);
            }
            const bf16x8 af1 = __builtin_bit_cast(bf16x8, a1);
            const bf16x8 af2 = __builtin_bit_cast(bf16x8, a2);
            __builtin_amdgcn_s_setprio(1);
            acc0 = __builtin_amdgcn_mfma_f32_32x32x16_bf16(af1, b00, acc0, 0, 0, 0);
            acc1 = __builtin_amdgcn_mfma_f32_32x32x16_bf16(af1, b01, acc1, 0, 0, 0);
            acc0 = __builtin_amdgcn_mfma_f32_32x32x16_bf16(af2, b10, acc0, 0, 0, 0);
            acc1 = __builtin_amdgcn_mfma_f32_32x32x16_bf16(af2, b11, acc1, 0, 0, 0);
            __builtin_amdgcn_s_setprio(0);
            // advance phases: elementwise f32x2 -> v_pk_mul/v_pk_fma_f32
            #pragma unroll
            for (int qq = 0; qq < 4; ++qq) {
                const f32x2 c = vc[qq], s = vs[qq];
                vc[qq] = c * vbc[qq] - s * vbs[qq];
                vs[qq] = s * vbc[qq] + c * vbs[qq];
            }
        }
        __syncthreads();   // drains vm+lgkm: next buf landed; this buf's reads sealed
    }

    // epilogue: D layout (32x32): col=lane&31, row=(r&3)+8*(r>>2)+4*(lane>>5)
    #pragma unroll
    for (int r = 0; r < 16; ++r) {
        const int orow = mtile * 128 + wave * 32 + (r & 3) + 8 * (r >> 2) + 4 * kgrp;
        unsafeAtomicAdd(out + (size_t)orow * ODIM + l31, acc0[r]);
        unsafeAtomicAdd(out + (size_t)orow * ODIM + 32 + l31, acc1[r]);
    }
}

// ---------------------------------------------------------------------------
// Fallback (ws too small): exact fp32, one thread per (b,j). Slow but correct.
// ---------------------------------------------------------------------------
__global__ __launch_bounds__(256) void fkan_naive(const float* __restrict__ x,
                                                  const float* __restrict__ fc,
                                                  float* __restrict__ out) {
    const int j = blockIdx.x >> 3;
    const int b = (blockIdx.x & 7) * 256 + threadIdx.x;
    const float* xr = x + (size_t)b * IDIM;
    float acc = 0.f;
    for (int i = 0; i < IDIM; ++i) {
        const float xv = xr[i];
        float sb, cb;
        __sincosf(xv, &sb, &cb);
        float c = cb, s = sb;
        const float* wc = fc + ((size_t)j * IDIM + i) * GRIDN;
        const float* ws = wc + (size_t)ODIM * IDIM * GRIDN;
        for (int g = 0; g < GRIDN; ++g) {
            acc += c * wc[g] + s * ws[g];
            const float cn = c * cb - s * sb;
            s = s * cb + c * sb;
            c = cn;
        }
    }
    out[(size_t)b * ODIM + j] = acc;
}

extern "C" void kernel_launch(void* const* d_in, const int* in_sizes, int n_in,
                              void* d_out, int out_size, void* d_ws, size_t ws_size,
                              hipStream_t stream) {
    const float* x  = (const float*)d_in[0];
    const float* fc = (const float*)d_in[1];
    float* out = (float*)d_out;
    constexpr size_t WPB = 16ull * GRIDN * 4096;   // 19.66 MB bf16 weight image

    if (ws_size >= WPB) {
        hipMemsetAsync(d_out, 0, (size_t)out_size * sizeof(float), stream);
        fkan_prep<<<608, 256, 0, stream>>>(fc, (char*)d_ws);
        fkan_main<<<1280, 256, 0, stream>>>(x, (const char*)d_ws, out);
    } else {
        fkan_naive<<<512, 256, 0, stream>>>(x, fc, out);
    }
}

// Round 9
// 85.717 us; speedup vs baseline: 1.2473x; 1.2473x over previous
//
#include <hip/hip_runtime.h>
#include <hip/hip_bf16.h>

#define BATCH 2048
#define IDIM  256
#define ODIM  64
#define GRIDN 300

typedef __bf16 bf16x8 __attribute__((ext_vector_type(8)));
typedef float  f32x16 __attribute__((ext_vector_type(16)));
typedef float  f32x2  __attribute__((ext_vector_type(2)));
typedef unsigned int uint4v __attribute__((ext_vector_type(4)));

#define AS1 __attribute__((address_space(1)))
#define AS3 __attribute__((address_space(3)))

// NO unions in hot paths (R4/R5/R6: memory-typed aggregates scratch-demote).
// NO launch_bounds tighter than the natural allocation (R8: (256,5) forced
// VGPR 64->48 and spilled ~31MB/dispatch). Vectors + bit_cast only.
__device__ __forceinline__ unsigned short f2bf(float f) {
    return __builtin_bit_cast(unsigned short, __float2bfloat16(f));  // RNE
}

// ---------------------------------------------------------------------------
// Prep (unchanged — proven): fouriercoeffs [2][64][256][300] f32 -> WP bf16
// 4KB chunks, one per (isplit ib, g).
// In-chunk byte = q*1024 + j*16 + (il&3)*4 + t*2, q = il>>2.
// ---------------------------------------------------------------------------
__global__ __launch_bounds__(256) void fkan_prep(const float* __restrict__ fc,
                                                 char* __restrict__ wp) {
    __shared__ alignas(16) char lds[32768];
    const int blk = blockIdx.x;
    const int ib  = blk & 15;          // i-split 0..15
    const int gb  = blk >> 4;          // 0..37
    const int g0  = gb * 8;
    const int G   = (gb == 37) ? 4 : 8;   // 300 = 37*8 + 4
    const int q   = threadIdx.x >> 6;     // wave = il quad
    const int j   = threadIdx.x & 63;     // lane = output col

    float vals[2][4][8];
    #pragma unroll
    for (int t = 0; t < 2; ++t) {
        #pragma unroll
        for (int e = 0; e < 4; ++e) {
            const float* src = fc + (((size_t)t * ODIM + j) * IDIM
                                     + (ib * 16 + q * 4 + e)) * GRIDN + g0;
            float4 lo = *(const float4*)(src);
            vals[t][e][0] = lo.x; vals[t][e][1] = lo.y;
            vals[t][e][2] = lo.z; vals[t][e][3] = lo.w;
            if (G == 8) {
                float4 hi = *(const float4*)(src + 4);
                vals[t][e][4] = hi.x; vals[t][e][5] = hi.y;
                vals[t][e][6] = hi.z; vals[t][e][7] = hi.w;
            }
        }
    }
    #pragma unroll
    for (int g = 0; g < 8; ++g) {
        if (g < 4 || G == 8) {
            uint4v dw;
            #pragma unroll
            for (int e = 0; e < 4; ++e)
                dw[e] = (unsigned)f2bf(vals[0][e][g]) | ((unsigned)f2bf(vals[1][e][g]) << 16);
            *(uint4v*)(lds + g * 4096 + q * 1024 + j * 16) = dw;
        }
    }
    __syncthreads();
    char* dst = wp + ((size_t)ib * GRIDN + g0) * 4096;
    for (int w = threadIdx.x * 16; w < G * 4096; w += 256 * 16)
        *(uint4v*)(dst + w) = *(const uint4v*)(lds + w);
}

// ---------------------------------------------------------------------------
// Main — R7's proven union-free hot loop under (256,4) (known-good codegen:
// 64 VGPR + 32 AGPR, zero spill), with the ONLY change being residency:
//  * 3-g (12KB) stages, LDS 2x12KB = 24KB/block.
//    Capacity/CU = min(LDS 160/24 = 6, regs 512/96 = 5) = 5 blocks.
//  * grid 1024 (4 gq x 75 g, 25 iters x 3 g) = 4 blocks/CU -> ALL blocks
//    co-resident from t=0, zero tail (R7: 40KB blocks -> 3/CU + ragged tail,
//    29% occupancy).
//  * f32x2 recurrence states (same 32 floats of register state as scalar,
//    half the instructions via v_pk_fma_f32).
// Race-free (3x proven): next-stage DMAs issued only after the __syncthreads
// that drained vm+lgkm -> destination buffer's reads all landed in registers.
// Grid mapping: xcd = bid&7; each XCD's 128 blocks touch exactly 2 isplits
// (2 x 1.2MB weight slice -> L2-resident).
// ---------------------------------------------------------------------------
__global__ __launch_bounds__(256, 4) void fkan_main(const float* __restrict__ x,
                                                    const char* __restrict__ wp,
                                                    float* __restrict__ out) {
    __shared__ alignas(16) char lds[2][12288];

    const int bid    = blockIdx.x;               // 0..1023
    const int xcd    = bid & 7;
    const int within = bid >> 3;                 // 0..127
    const int slice  = xcd * 8 + (within & 7);   // 0..63  (isplit x gq)
    const int mtile  = within >> 3;              // 0..15
    const int isplit = slice >> 2;               // 0..15
    const int gq     = slice & 3;                // 0..3
    const int g_begin = gq * 75;

    const int tid  = threadIdx.x;
    const int wave = tid >> 6;
    const int lane = tid & 63;
    const int l31  = lane & 31;
    const int kgrp = lane >> 5;
    const int row  = mtile * 128 + wave * 32 + l31;   // batch row (A lane row)

    // --- init 8 recurrence states, packed as f32x2 (v_pk_fma_f32 path) ---
    // state ss = h*4+p  <->  il = h*8 + kgrp*4 + p;  vc[ss>>1][ss&1] = cos
    f32x2 vc[4], vs[4], vbc[4], vbs[4];
    const float* xrow = x + (size_t)row * IDIM + isplit * 16;
    #pragma unroll
    for (int h = 0; h < 2; ++h) {
        const float4 xv4 = *(const float4*)(xrow + h * 8 + kgrp * 4);
        float xa[4] = {xv4.x, xv4.y, xv4.z, xv4.w};
        #pragma unroll
        for (int p = 0; p < 4; ++p) {
            const int ss = h * 4 + p;
            const float xv = xa[p];
            float sb, cb;
            __sincosf(xv, &sb, &cb);
            vbc[ss >> 1][ss & 1] = cb; vbs[ss >> 1][ss & 1] = sb;
            float s0 = sb, c0 = cb;
            if (g_begin != 0) __sincosf((float)(g_begin + 1) * xv, &s0, &c0);
            vc[ss >> 1][ss & 1] = c0; vs[ss >> 1][ss & 1] = s0;
        }
    }

    // B-frag read base inside a 4KB g-slice: q*1024 + j*16, q = kchunk*2+kgrp
    const unsigned aq = (unsigned)kgrp * 1024 + (unsigned)l31 * 16;
    const char* wbase = wp + ((size_t)(isplit * GRIDN + g_begin)) * 4096 + tid * 16;

    // prologue: stage iter-0's 3 g-slices (12KB) into buf 0
    #pragma unroll
    for (int p = 0; p < 3; ++p)
        __builtin_amdgcn_global_load_lds(
            (const AS1 unsigned int*)(wbase + (size_t)p * 4096),
            (AS3 unsigned int*)(&lds[0][0] + p * 4096 + tid * 16), 16, 0, 0);
    __syncthreads();

    f32x16 acc0 = {0,0,0,0,0,0,0,0,0,0,0,0,0,0,0,0};
    f32x16 acc1 = {0,0,0,0,0,0,0,0,0,0,0,0,0,0,0,0};

    for (int it = 0; it < 25; ++it) {
        const int cur = it & 1;
        // issue next 12KB stage; destination buffer's reads were sealed by the
        // previous iteration's __syncthreads (vm+lgkm drained for all waves)
        if (it + 1 < 25) {
            #pragma unroll
            for (int p = 0; p < 3; ++p)
                __builtin_amdgcn_global_load_lds(
                    (const AS1 unsigned int*)(wbase + ((size_t)(it + 1) * 3 + p) * 4096),
                    (AS3 unsigned int*)(&lds[cur ^ 1][0] + p * 4096 + tid * 16),
                    16, 0, 0);
        }
        #pragma unroll
        for (int g = 0; g < 3; ++g) {
            const char* base = &lds[cur][0] + g * 4096;
            const bf16x8 b00 = *(const bf16x8*)(base + aq);           // kc0, cols 0..31
            const bf16x8 b01 = *(const bf16x8*)(base + aq + 512);     // kc0, cols 32..63
            const bf16x8 b10 = *(const bf16x8*)(base + aq + 2048);    // kc1, cols 0..31
            const bf16x8 b11 = *(const bf16x8*)(base + aq + 2560);    // kc1, cols 32..63
            uint4v a1, a2;
            #pragma unroll
            for (int p = 0; p < 4; ++p) {
                a1[p] = (unsigned)f2bf(vc[p >> 1][p & 1])
                      | ((unsigned)f2bf(vs[p >> 1][p & 1]) << 16);
                a2[p] = (unsigned)f2bf(vc[(4 + p) >> 1][p & 1])
                      | ((unsigned)f2bf(vs[(4 + p) >> 1][p & 1]) << 16);
            }
            const bf16x8 af1 = __builtin_bit_cast(bf16x8, a1);
            const bf16x8 af2 = __builtin_bit_cast(bf16x8, a2);
            __builtin_amdgcn_s_setprio(1);
            acc0 = __builtin_amdgcn_mfma_f32_32x32x16_bf16(af1, b00, acc0, 0, 0, 0);
            acc1 = __builtin_amdgcn_mfma_f32_32x32x16_bf16(af1, b01, acc1, 0, 0, 0);
            acc0 = __builtin_amdgcn_mfma_f32_32x32x16_bf16(af2, b10, acc0, 0, 0, 0);
            acc1 = __builtin_amdgcn_mfma_f32_32x32x16_bf16(af2, b11, acc1, 0, 0, 0);
            __builtin_amdgcn_s_setprio(0);
            // advance phases: elementwise f32x2 -> v_pk_mul/v_pk_fma_f32
            #pragma unroll
            for (int qq = 0; qq < 4; ++qq) {
                const f32x2 c = vc[qq], s = vs[qq];
                vc[qq] = c * vbc[qq] - s * vbs[qq];
                vs[qq] = s * vbc[qq] + c * vbs[qq];
            }
        }
        __syncthreads();   // drains vm+lgkm: next buf landed; this buf's reads sealed
    }

    // epilogue: D layout (32x32): col=lane&31, row=(r&3)+8*(r>>2)+4*(lane>>5)
    #pragma unroll
    for (int r = 0; r < 16; ++r) {
        const int orow = mtile * 128 + wave * 32 + (r & 3) + 8 * (r >> 2) + 4 * kgrp;
        unsafeAtomicAdd(out + (size_t)orow * ODIM + l31, acc0[r]);
        unsafeAtomicAdd(out + (size_t)orow * ODIM + 32 + l31, acc1[r]);
    }
}

// ---------------------------------------------------------------------------
// Fallback (ws too small): exact fp32, one thread per (b,j). Slow but correct.
// ---------------------------------------------------------------------------
__global__ __launch_bounds__(256) void fkan_naive(const float* __restrict__ x,
                                                  const float* __restrict__ fc,
                                                  float* __restrict__ out) {
    const int j = blockIdx.x >> 3;
    const int b = (blockIdx.x & 7) * 256 + threadIdx.x;
    const float* xr = x + (size_t)b * IDIM;
    float acc = 0.f;
    for (int i = 0; i < IDIM; ++i) {
        const float xv = xr[i];
        float sb, cb;
        __sincosf(xv, &sb, &cb);
        float c = cb, s = sb;
        const float* wc = fc + ((size_t)j * IDIM + i) * GRIDN;
        const float* ws = wc + (size_t)ODIM * IDIM * GRIDN;
        for (int g = 0; g < GRIDN; ++g) {
            acc += c * wc[g] + s * ws[g];
            const float cn = c * cb - s * sb;
            s = s * cb + c * sb;
            c = cn;
        }
    }
    out[(size_t)b * ODIM + j] = acc;
}

extern "C" void kernel_launch(void* const* d_in, const int* in_sizes, int n_in,
                              void* d_out, int out_size, void* d_ws, size_t ws_size,
                              hipStream_t stream) {
    const float* x  = (const float*)d_in[0];
    const float* fc = (const float*)d_in[1];
    float* out = (float*)d_out;
    constexpr size_t WPB = 16ull * GRIDN * 4096;   // 19.66 MB bf16 weight image

    if (ws_size >= WPB) {
        hipMemsetAsync(d_out, 0, (size_t)out_size * sizeof(float), stream);
        fkan_prep<<<608, 256, 0, stream>>>(fc, (char*)d_ws);
        fkan_main<<<1024, 256, 0, stream>>>(x, (const char*)d_ws, out);
    } else {
        fkan_naive<<<512, 256, 0, stream>>>(x, fc, out);
    }
}

// Round 10
// 78.580 us; speedup vs baseline: 1.3606x; 1.0908x over previous
//
#include <hip/hip_runtime.h>
#include <hip/hip_bf16.h>

#define BATCH 2048
#define IDIM  256
#define ODIM  64
#define GRIDN 300

typedef __bf16 bf16x8 __attribute__((ext_vector_type(8)));
typedef float  f32x16 __attribute__((ext_vector_type(16)));
typedef float  f32x2  __attribute__((ext_vector_type(2)));
typedef unsigned int uint4v __attribute__((ext_vector_type(4)));

#define AS1 __attribute__((address_space(1)))
#define AS3 __attribute__((address_space(3)))

// NO unions in hot paths (R4/R5/R6: memory-typed aggregates scratch-demote).
// NO launch_bounds tighter than natural allocation (R8: (256,5) spilled).
// NO __float2bfloat16 in hot loops (R9: it's a ~5-inst SOFTWARE RNE sequence;
// 16/wave-g = ~60% of all VALU). Hot path uses hardware v_cvt_pk_bf16_f32.
__device__ __forceinline__ unsigned short f2bf(float f) {   // cold paths only
    return __builtin_bit_cast(unsigned short, __float2bfloat16(f));
}

// ---------------------------------------------------------------------------
// Prep (unchanged — proven): fouriercoeffs [2][64][256][300] f32 -> WP bf16
// 4KB chunks, one per (isplit ib, g).
// In-chunk byte = q*1024 + j*16 + (il&3)*4 + t*2, q = il>>2.
// ---------------------------------------------------------------------------
__global__ __launch_bounds__(256) void fkan_prep(const float* __restrict__ fc,
                                                 char* __restrict__ wp) {
    __shared__ alignas(16) char lds[32768];
    const int blk = blockIdx.x;
    const int ib  = blk & 15;          // i-split 0..15
    const int gb  = blk >> 4;          // 0..37
    const int g0  = gb * 8;
    const int G   = (gb == 37) ? 4 : 8;   // 300 = 37*8 + 4
    const int q   = threadIdx.x >> 6;     // wave = il quad
    const int j   = threadIdx.x & 63;     // lane = output col

    float vals[2][4][8];
    #pragma unroll
    for (int t = 0; t < 2; ++t) {
        #pragma unroll
        for (int e = 0; e < 4; ++e) {
            const float* src = fc + (((size_t)t * ODIM + j) * IDIM
                                     + (ib * 16 + q * 4 + e)) * GRIDN + g0;
            float4 lo = *(const float4*)(src);
            vals[t][e][0] = lo.x; vals[t][e][1] = lo.y;
            vals[t][e][2] = lo.z; vals[t][e][3] = lo.w;
            if (G == 8) {
                float4 hi = *(const float4*)(src + 4);
                vals[t][e][4] = hi.x; vals[t][e][5] = hi.y;
                vals[t][e][6] = hi.z; vals[t][e][7] = hi.w;
            }
        }
    }
    #pragma unroll
    for (int g = 0; g < 8; ++g) {
        if (g < 4 || G == 8) {
            uint4v dw;
            #pragma unroll
            for (int e = 0; e < 4; ++e)
                dw[e] = (unsigned)f2bf(vals[0][e][g]) | ((unsigned)f2bf(vals[1][e][g]) << 16);
            *(uint4v*)(lds + g * 4096 + q * 1024 + j * 16) = dw;
        }
    }
    __syncthreads();
    char* dst = wp + ((size_t)ib * GRIDN + g0) * 4096;
    for (int w = threadIdx.x * 16; w < G * 4096; w += 256 * 16)
        *(uint4v*)(dst + w) = *(const uint4v*)(lds + w);
}

// ---------------------------------------------------------------------------
// Main — R9's clean structure (zero spill: FETCH 10.7MB / WRITE 32.8MB),
// ONE change: A-fragments built with hardware v_cvt_pk_bf16_f32 (dst.lo =
// src0 = cos, dst.hi = src1 = sin -> matches layout dword = cos | sin<<16).
// 8 asm insts replace ~88 software-RNE insts per wave-g (R9: VALUBusy 52%,
// ~60% of it __float2bfloat16 emulation). Pure-VALU asm, explicit operands,
// no clobbers -> no scheduling hazard (rule-18 applies only to memory asm).
// Race-free (4x proven): next-stage DMAs issued only after the __syncthreads
// that sealed all reads of the destination buffer.
// ---------------------------------------------------------------------------
__global__ __launch_bounds__(256, 4) void fkan_main(const float* __restrict__ x,
                                                    const char* __restrict__ wp,
                                                    float* __restrict__ out) {
    __shared__ alignas(16) char lds[2][12288];

    const int bid    = blockIdx.x;               // 0..1023
    const int xcd    = bid & 7;
    const int within = bid >> 3;                 // 0..127
    const int slice  = xcd * 8 + (within & 7);   // 0..63  (isplit x gq)
    const int mtile  = within >> 3;              // 0..15
    const int isplit = slice >> 2;               // 0..15
    const int gq     = slice & 3;                // 0..3
    const int g_begin = gq * 75;

    const int tid  = threadIdx.x;
    const int wave = tid >> 6;
    const int lane = tid & 63;
    const int l31  = lane & 31;
    const int kgrp = lane >> 5;
    const int row  = mtile * 128 + wave * 32 + l31;   // batch row (A lane row)

    // --- init 8 recurrence states, packed as f32x2 (v_pk_fma_f32 path) ---
    // state ss = h*4+p  <->  il = h*8 + kgrp*4 + p;  vc[ss>>1][ss&1] = cos
    f32x2 vc[4], vs[4], vbc[4], vbs[4];
    const float* xrow = x + (size_t)row * IDIM + isplit * 16;
    #pragma unroll
    for (int h = 0; h < 2; ++h) {
        const float4 xv4 = *(const float4*)(xrow + h * 8 + kgrp * 4);
        float xa[4] = {xv4.x, xv4.y, xv4.z, xv4.w};
        #pragma unroll
        for (int p = 0; p < 4; ++p) {
            const int ss = h * 4 + p;
            const float xv = xa[p];
            float sb, cb;
            __sincosf(xv, &sb, &cb);
            vbc[ss >> 1][ss & 1] = cb; vbs[ss >> 1][ss & 1] = sb;
            float s0 = sb, c0 = cb;
            if (g_begin != 0) __sincosf((float)(g_begin + 1) * xv, &s0, &c0);
            vc[ss >> 1][ss & 1] = c0; vs[ss >> 1][ss & 1] = s0;
        }
    }

    // B-frag read base inside a 4KB g-slice: q*1024 + j*16, q = kchunk*2+kgrp
    const unsigned aq = (unsigned)kgrp * 1024 + (unsigned)l31 * 16;
    const char* wbase = wp + ((size_t)(isplit * GRIDN + g_begin)) * 4096 + tid * 16;

    // prologue: stage iter-0's 3 g-slices (12KB) into buf 0
    #pragma unroll
    for (int p = 0; p < 3; ++p)
        __builtin_amdgcn_global_load_lds(
            (const AS1 unsigned int*)(wbase + (size_t)p * 4096),
            (AS3 unsigned int*)(&lds[0][0] + p * 4096 + tid * 16), 16, 0, 0);
    __syncthreads();

    f32x16 acc0 = {0,0,0,0,0,0,0,0,0,0,0,0,0,0,0,0};
    f32x16 acc1 = {0,0,0,0,0,0,0,0,0,0,0,0,0,0,0,0};

    for (int it = 0; it < 25; ++it) {
        const int cur = it & 1;
        // issue next 12KB stage; destination buffer's reads were sealed by the
        // previous iteration's __syncthreads (vm+lgkm drained for all waves)
        if (it + 1 < 25) {
            #pragma unroll
            for (int p = 0; p < 3; ++p)
                __builtin_amdgcn_global_load_lds(
                    (const AS1 unsigned int*)(wbase + ((size_t)(it + 1) * 3 + p) * 4096),
                    (AS3 unsigned int*)(&lds[cur ^ 1][0] + p * 4096 + tid * 16),
                    16, 0, 0);
        }
        #pragma unroll
        for (int g = 0; g < 3; ++g) {
            const char* base = &lds[cur][0] + g * 4096;
            const bf16x8 b00 = *(const bf16x8*)(base + aq);           // kc0, cols 0..31
            const bf16x8 b01 = *(const bf16x8*)(base + aq + 512);     // kc0, cols 32..63
            const bf16x8 b10 = *(const bf16x8*)(base + aq + 2048);    // kc1, cols 0..31
            const bf16x8 b11 = *(const bf16x8*)(base + aq + 2560);    // kc1, cols 32..63
            // A-frags: HW packed convert. dword p = bf16(cos_p) | bf16(sin_p)<<16
            uint4v a1, a2;
            #pragma unroll
            for (int p = 0; p < 4; ++p) {
                const float c1f = vc[p >> 1][p & 1],     s1f = vs[p >> 1][p & 1];
                const float c2f = vc[2 + (p >> 1)][p & 1], s2f = vs[2 + (p >> 1)][p & 1];
                unsigned r1, r2;
                asm("v_cvt_pk_bf16_f32 %0, %1, %2" : "=v"(r1) : "v"(c1f), "v"(s1f));
                asm("v_cvt_pk_bf16_f32 %0, %1, %2" : "=v"(r2) : "v"(c2f), "v"(s2f));
                a1[p] = r1; a2[p] = r2;
            }
            const bf16x8 af1 = __builtin_bit_cast(bf16x8, a1);
            const bf16x8 af2 = __builtin_bit_cast(bf16x8, a2);
            __builtin_amdgcn_s_setprio(1);
            acc0 = __builtin_amdgcn_mfma_f32_32x32x16_bf16(af1, b00, acc0, 0, 0, 0);
            acc1 = __builtin_amdgcn_mfma_f32_32x32x16_bf16(af1, b01, acc1, 0, 0, 0);
            acc0 = __builtin_amdgcn_mfma_f32_32x32x16_bf16(af2, b10, acc0, 0, 0, 0);
            acc1 = __builtin_amdgcn_mfma_f32_32x32x16_bf16(af2, b11, acc1, 0, 0, 0);
            __builtin_amdgcn_s_setprio(0);
            // advance phases: elementwise f32x2 -> v_pk_mul/v_pk_fma_f32
            #pragma unroll
            for (int qq = 0; qq < 4; ++qq) {
                const f32x2 c = vc[qq], s = vs[qq];
                vc[qq] = c * vbc[qq] - s * vbs[qq];
                vs[qq] = s * vbc[qq] + c * vbs[qq];
            }
        }
        __syncthreads();   // drains vm+lgkm: next buf landed; this buf's reads sealed
    }

    // epilogue: D layout (32x32): col=lane&31, row=(r&3)+8*(r>>2)+4*(lane>>5)
    #pragma unroll
    for (int r = 0; r < 16; ++r) {
        const int orow = mtile * 128 + wave * 32 + (r & 3) + 8 * (r >> 2) + 4 * kgrp;
        unsafeAtomicAdd(out + (size_t)orow * ODIM + l31, acc0[r]);
        unsafeAtomicAdd(out + (size_t)orow * ODIM + 32 + l31, acc1[r]);
    }
}

// ---------------------------------------------------------------------------
// Fallback (ws too small): exact fp32, one thread per (b,j). Slow but correct.
// ---------------------------------------------------------------------------
__global__ __launch_bounds__(256) void fkan_naive(const float* __restrict__ x,
                                                  const float* __restrict__ fc,
                                                  float* __restrict__ out) {
    const int j = blockIdx.x >> 3;
    const int b = (blockIdx.x & 7) * 256 + threadIdx.x;
    const float* xr = x + (size_t)b * IDIM;
    float acc = 0.f;
    for (int i = 0; i < IDIM; ++i) {
        const float xv = xr[i];
        float sb, cb;
        __sincosf(xv, &sb, &cb);
        float c = cb, s = sb;
        const float* wc = fc + ((size_t)j * IDIM + i) * GRIDN;
        const float* ws = wc + (size_t)ODIM * IDIM * GRIDN;
        for (int g = 0; g < GRIDN; ++g) {
            acc += c * wc[g] + s * ws[g];
            const float cn = c * cb - s * sb;
            s = s * cb + c * sb;
            c = cn;
        }
    }
    out[(size_t)b * ODIM + j] = acc;
}

extern "C" void kernel_launch(void* const* d_in, const int* in_sizes, int n_in,
                              void* d_out, int out_size, void* d_ws, size_t ws_size,
                              hipStream_t stream) {
    const float* x  = (const float*)d_in[0];
    const float* fc = (const float*)d_in[1];
    float* out = (float*)d_out;
    constexpr size_t WPB = 16ull * GRIDN * 4096;   // 19.66 MB bf16 weight image

    if (ws_size >= WPB) {
        hipMemsetAsync(d_out, 0, (size_t)out_size * sizeof(float), stream);
        fkan_prep<<<608, 256, 0, stream>>>(fc, (char*)d_ws);
        fkan_main<<<1024, 256, 0, stream>>>(x, (const char*)d_ws, out);
    } else {
        fkan_naive<<<512, 256, 0, stream>>>(x, fc, out);
    }
}